// Round 3
// baseline (227.670 us; speedup 1.0000x reference)
//
#include <hip/hip_runtime.h>
#include <math.h>

// N = 160000 = 256 * 625; four-step FFT decomposition.
// Forward:  x[256*n2 + n1] --(625-FFT over n2, per n1; twiddle W_N^{n1 k2})-->
//           G'[k2][n1]     --(256-FFT over n1, per k2)--> X[k2][k1] = bin 625*k1+k2
// Inverse:  Y[k2][k1] --(256-pt sign+ FFT over k1; twiddle e^{+2pi i n1 k2/N})-->
//           H'[n1][k2] --(625-pt sign+ FFT over k2)--> N*y[256*n2 + n1]
// All twiddles come from one table W[k] = e^{-2pi i k / L} (1.28 MB, L2/L3 hot).
constexpr int L      = 160000;
constexpr int BATCH  = 8;
constexpr int NB     = 8;
constexpr int NHOPS  = 156;   // 1024-sample hop sums
constexpr int NCHUNK = 155;   // 2048-windows, hop 1024
constexpr float TWO_PI = 6.28318530717958647692f;

__device__ __forceinline__ float2 cmulf(float2 a, float2 b) {
  return make_float2(a.x * b.x - a.y * b.y, a.x * b.y + a.y * b.x);
}

// ---------- signed butterflies (SIGN=-1 forward e^{-i}, +1 inverse e^{+i}) ----------
template <int SIGN>
__device__ __forceinline__ void bf4s(float2* v) {
  float2 t0 = make_float2(v[0].x + v[2].x, v[0].y + v[2].y);
  float2 t1 = make_float2(v[0].x - v[2].x, v[0].y - v[2].y);
  float2 t2 = make_float2(v[1].x + v[3].x, v[1].y + v[3].y);
  float2 t3 = make_float2(v[1].x - v[3].x, v[1].y - v[3].y);
  v[0] = make_float2(t0.x + t2.x, t0.y + t2.y);
  v[2] = make_float2(t0.x - t2.x, t0.y - t2.y);
  if constexpr (SIGN < 0) {
    v[1] = make_float2(t1.x + t3.y, t1.y - t3.x);   // t1 - i t3
    v[3] = make_float2(t1.x - t3.y, t1.y + t3.x);   // t1 + i t3
  } else {
    v[1] = make_float2(t1.x - t3.y, t1.y + t3.x);
    v[3] = make_float2(t1.x + t3.y, t1.y - t3.x);
  }
}

template <int SIGN>
__device__ __forceinline__ void bf5s(float2* v) {
  const float c1 = 0.30901699437494745f, s1 = 0.9510565162951535f;
  const float c2 = -0.8090169943749475f, s2 = 0.5877852522924731f;
  float2 t1 = make_float2(v[1].x + v[4].x, v[1].y + v[4].y);
  float2 t3 = make_float2(v[1].x - v[4].x, v[1].y - v[4].y);
  float2 t2 = make_float2(v[2].x + v[3].x, v[2].y + v[3].y);
  float2 t4 = make_float2(v[2].x - v[3].x, v[2].y - v[3].y);
  float2 a = make_float2(v[0].x + c1 * t1.x + c2 * t2.x, v[0].y + c1 * t1.y + c2 * t2.y);
  float2 b = make_float2(s1 * t3.x + s2 * t4.x, s1 * t3.y + s2 * t4.y);
  float2 c = make_float2(v[0].x + c2 * t1.x + c1 * t2.x, v[0].y + c2 * t1.y + c1 * t2.y);
  float2 d = make_float2(s2 * t3.x - s1 * t4.x, s2 * t3.y - s1 * t4.y);
  v[0] = make_float2(v[0].x + t1.x + t2.x, v[0].y + t1.y + t2.y);
  if constexpr (SIGN < 0) {
    v[1] = make_float2(a.x + b.y, a.y - b.x);  // a - i b
    v[4] = make_float2(a.x - b.y, a.y + b.x);
    v[2] = make_float2(c.x + d.y, c.y - d.x);  // c - i d
    v[3] = make_float2(c.x + d.y * -1.0f, c.y + d.x);
  } else {
    v[1] = make_float2(a.x - b.y, a.y + b.x);  // a + i b
    v[4] = make_float2(a.x + b.y, a.y - b.x);
    v[2] = make_float2(c.x - d.y, c.y + d.x);
    v[3] = make_float2(c.x + d.y, c.y - d.x);
  }
}

// ---------- one Stockham stage in LDS, per-wave private region, NO barriers ----------
// Twiddle: e^{SIGN*2pi i * r*jm/(R*Ns)} = (conj^)W[r*jm*STEP], STEP = L/(R*Ns).
// Loaded once (r=1) then chained: t_r = t_{r-1} * t_1.
template <int R, int Ns, int STEP, int SIGN, int M>
__device__ __forceinline__ void lds_stage(const float2* in, float2* out, int w,
                                          const float2* __restrict__ W) {
  constexpr int NR = M / R;
  for (int j = w; j < NR; j += 64) {
    float2 v[R];
#pragma unroll
    for (int r = 0; r < R; ++r) v[r] = in[j + r * NR];
    int jm = 0;
    if constexpr (Ns > 1) {
      jm = j % Ns;
      float2 t1 = W[jm * STEP];
      if constexpr (SIGN > 0) t1.y = -t1.y;
      float2 t = t1;
      v[1] = cmulf(v[1], t);
#pragma unroll
      for (int r = 2; r < R; ++r) { t = cmulf(t, t1); v[r] = cmulf(v[r], t); }
    }
    if constexpr (R == 4) bf4s<SIGN>(v); else bf5s<SIGN>(v);
    int od = (j / Ns) * (Ns * R) + jm;
#pragma unroll
    for (int r = 0; r < R; ++r) out[od + r * Ns] = v[r];
  }
}

// Per-wave 625-pt FFT in a private LDS slice. Result lands in `a`.
// No __syncthreads(): same-wave LDS ordering is enforced by lgkmcnt waits.
template <int SIGN>
__device__ __forceinline__ void fft625(float2* a, float2* b, int w, const float2* W) {
  lds_stage<5, 1,   0,    SIGN, 625>(a, b, w, W);
  lds_stage<5, 5,   6400, SIGN, 625>(b, a, w, W);
  lds_stage<5, 25,  1280, SIGN, 625>(a, b, w, W);
  lds_stage<5, 125, 256,  SIGN, 625>(b, a, w, W);
}

template <int SIGN>
__device__ __forceinline__ void fft256(float2* a, float2* b, int w, const float2* W) {
  lds_stage<4, 1,  0,     SIGN, 256>(a, b, w, W);
  lds_stage<4, 4,  10000, SIGN, 256>(b, a, w, W);
  lds_stage<4, 16, 2500,  SIGN, 256>(a, b, w, W);
  lds_stage<4, 64, 625,   SIGN, 256>(b, a, w, W);
}

// ---------- setup: W[k] = e^{-2pi i k/L} ----------
__global__ __launch_bounds__(256) void setup_kernel(float2* __restrict__ W) {
  int k = blockIdx.x * 256 + threadIdx.x;
  if (k < L) {
    float s, c;
    sincosf(-TWO_PI * ((float)k / (float)L), &s, &c);
    W[k] = make_float2(c, s);
  }
}

// ---------- F1: pack w+i*o, 625-FFT columns, twiddle, store transposed [k2][n1] ----------
__global__ __launch_bounds__(256) void f1_kernel(const float* __restrict__ win,
                                                 const float* __restrict__ oin,
                                                 float2* __restrict__ G,
                                                 const float2* __restrict__ W) {
  __shared__ float2 A[4 * 625], B[4 * 625];
  int blk = blockIdx.x;
  int sig = blk >> 6, g = blk & 63;          // 64 groups of 4 columns
  int n1base = g * 4;
  int tid = threadIdx.x;
  const float* wp = win + (size_t)sig * L;
  const float* op = oin + (size_t)sig * L;
  for (int idx = tid; idx < 2500; idx += 256) {
    int r = idx >> 2, cc = idx & 3;
    int n = (r << 8) + n1base + cc;
    A[cc * 625 + r] = make_float2(wp[n], op[n]);
  }
  __syncthreads();
  int wv = tid >> 6, ln = tid & 63;
  fft625<-1>(A + wv * 625, B + wv * 625, ln, W);
  __syncthreads();
  for (int idx = tid; idx < 2500; idx += 256) {
    int k2 = idx >> 2, cc = idx & 3;
    int n1 = n1base + cc;
    G[(size_t)sig * L + k2 * 256 + n1] = cmulf(A[cc * 625 + k2], W[n1 * k2]);
  }
}

// ---------- F2: 256-FFT along contiguous rows -> spectrum X[k2][k1] ----------
__global__ __launch_bounds__(256) void f2_kernel(const float2* __restrict__ G,
                                                 float2* __restrict__ X,
                                                 const float2* __restrict__ W) {
  __shared__ float2 A[4 * 257], B[4 * 257];   // +1 pad per row
  int blk = blockIdx.x;
  int sig = blk / 157, gr = blk % 157;
  int k2base = gr * 4;
  int tid = threadIdx.x;
  for (int idx = tid; idx < 1024; idx += 256) {
    int row = idx >> 8, k1 = idx & 255;
    int k2 = k2base + row;
    if (k2 < 625) A[row * 257 + k1] = G[(size_t)sig * L + k2 * 256 + k1];
  }
  __syncthreads();
  int wv = tid >> 6, ln = tid & 63;
  fft256<-1>(A + wv * 257, B + wv * 257, ln, W);
  __syncthreads();
  for (int idx = tid; idx < 1024; idx += 256) {
    int row = idx >> 8, k1 = idx & 255;
    int k2 = k2base + row;
    if (k2 < 625) X[(size_t)sig * L + k2 * 256 + k1] = A[row * 257 + k1];
  }
}

// ---------- I1: mask band inline, 256-pt sign+ FFT over k1, twiddle, store [n1][k2] ----------
__global__ __launch_bounds__(256) void i1_kernel(const float2* __restrict__ X,
                                                 float2* __restrict__ H,
                                                 const float2* __restrict__ W) {
  __shared__ float2 A[4 * 257], B[4 * 257];
  int blk = blockIdx.x;
  int gr = blk % 157, sb = blk / 157;
  int band = sb & 7, sig = sb >> 3;
  int k2base = gr * 4;
  int tid = threadIdx.x;
  for (int idx = tid; idx < 1024; idx += 256) {
    int row = idx >> 8, k1 = idx & 255;
    int k2 = k2base + row;
    if (k2 < 625) {
      int bin = 625 * k1 + k2;
      int m = min(bin, L - bin);
      int b = (m == 0) ? (NB - 1) : (m - 1) / 10000;
      float2 x = make_float2(0.0f, 0.0f);
      if (b == band) x = X[(size_t)sig * L + k2 * 256 + k1];
      A[row * 257 + k1] = x;
    }
  }
  __syncthreads();
  int wv = tid >> 6, ln = tid & 63;
  fft256<1>(A + wv * 257, B + wv * 257, ln, W);
  __syncthreads();
  size_t obase = (size_t)(sig * NB + band) * L;
  for (int idx = tid; idx < 1024; idx += 256) {
    int cc = idx & 3, n1 = idx >> 2;
    int k2 = k2base + cc;
    if (k2 < 625) {
      float2 t = W[n1 * k2];
      t.y = -t.y;                               // e^{+2pi i n1 k2 / L}
      H[obase + (size_t)n1 * 625 + k2] = cmulf(A[cc * 257 + n1], t);
    }
  }
}

// ---------- I2: 625-pt sign+ FFT over k2 + fused hop-energy reduction ----------
__global__ __launch_bounds__(256) void i2_kernel(const float2* __restrict__ H,
                                                 float* __restrict__ E,
                                                 const float2* __restrict__ W) {
  __shared__ float2 A[4 * 625], B[4 * 625];   // exactly 40000 B -> 4 blocks/CU
  float* P = (float*)B;                        // aliased: B is dead after fft625
  int blk = blockIdx.x;
  int g = blk & 63, sb = blk >> 6;
  int band = sb & 7, sig = sb >> 3;
  int n1base = g * 4;
  int tid = threadIdx.x;
  size_t ibase = (size_t)(sig * NB + band) * L;
#pragma unroll
  for (int row = 0; row < 4; ++row) {
    for (int k2 = tid; k2 < 625; k2 += 256) {
      A[row * 625 + k2] = H[ibase + (size_t)(n1base + row) * 625 + k2];
    }
  }
  __syncthreads();
  int wv = tid >> 6, ln = tid & 63;
  fft625<1>(A + wv * 625, B + wv * 625, ln, W);
  __syncthreads();                             // all waves done with B -> safe to alias P
  for (int idx = tid; idx < 2 * NHOPS; idx += 256) P[idx] = 0.0f;
  __syncthreads();
  // wave wv owns n1 = n1base+wv; S[n2] = N*(rw + i*ro) at n = 256*n2 + n1.
  // hop h == n2 in [4h, 4h+4) across all n1 (1024 = 4*256).
  constexpr float invN = 1.0f / (float)L;
  const float2* S = A + wv * 625;
  for (int h = ln; h < NHOPS; h += 64) {
    float ex = 0.0f, ey = 0.0f;
#pragma unroll
    for (int d = 0; d < 4; ++d) {
      float2 z = S[4 * h + d];
      float zx = z.x * invN, zy = z.y * invN;
      ex += zx * zx;
      ey += zy * zy;
    }
    atomicAdd(&P[h], ex);
    atomicAdd(&P[NHOPS + h], ey);
  }
  __syncthreads();
  int eb = (sig * NB + band) * NHOPS;
  for (int idx = tid; idx < 2 * NHOPS; idx += 256) {
    int comp = idx / NHOPS, h = idx % NHOPS;
    atomicAdd(&E[comp * (BATCH * NB * NHOPS) + eb + h], P[idx]);
  }
}

// ---------- finalize: loudness, diff, softmax-weighted sum ----------
__global__ void finalize_kernel(const float* __restrict__ E, float* __restrict__ out) {
  constexpr int ND = BATCH * NB * NCHUNK;  // 9920
  __shared__ float diffs[ND];
  __shared__ float sred[256];
  int tid = threadIdx.x;
  for (int idx = tid; idx < ND; idx += 256) {
    int sb = idx / NCHUNK;
    int k = idx - sb * NCHUNK;
    float hw0 = E[sb * NHOPS + k], hw1 = E[sb * NHOPS + k + 1];
    float ho0 = E[64 * NHOPS + sb * NHOPS + k], ho1 = E[64 * NHOPS + sb * NHOPS + k + 1];
    float msw = (hw0 + hw1) * (1.0f / 2048.0f);
    float mso = (ho0 + ho1) * (1.0f / 2048.0f);
    float lw = -0.691f + 10.0f * log10f(msw + 1e-12f);
    float lo = -0.691f + 10.0f * log10f(mso + 1e-12f);
    diffs[idx] = lw - lo;
  }
  __syncthreads();
  float mx = -3.4e38f;
  for (int idx = tid; idx < ND; idx += 256) mx = fmaxf(mx, diffs[idx]);
  sred[tid] = mx;
  __syncthreads();
  for (int s = 128; s > 0; s >>= 1) {
    if (tid < s) sred[tid] = fmaxf(sred[tid], sred[tid + s]);
    __syncthreads();
  }
  float gmax = sred[0];
  __syncthreads();
  float se = 0.0f, swd = 0.0f;
  for (int idx = tid; idx < ND; idx += 256) {
    float d = diffs[idx];
    float e = expf(d - gmax);
    se += e;
    swd += d * e;
  }
  sred[tid] = se; __syncthreads();
  for (int s = 128; s > 0; s >>= 1) { if (tid < s) sred[tid] += sred[tid + s]; __syncthreads(); }
  float tot = sred[0];
  __syncthreads();
  sred[tid] = swd; __syncthreads();
  for (int s = 128; s > 0; s >>= 1) { if (tid < s) sred[tid] += sred[tid + s]; __syncthreads(); }
  if (tid == 0) out[0] = sred[0] / tot;
}

extern "C" void kernel_launch(void* const* d_in, const int* in_sizes, int n_in,
                              void* d_out, int out_size, void* d_ws, size_t ws_size,
                              hipStream_t stream) {
  (void)in_sizes; (void)n_in; (void)out_size; (void)ws_size;
  char* ws = (char*)d_ws;
  float2* G = (float2*)ws;                        // 10,240,000 B
  float2* X = (float2*)(ws + 10240000);           // 10,240,000 B
  float2* H = (float2*)(ws + 20480000);           // 81,920,000 B
  float*  E = (float*)(ws + 102400000);           // 79,872 B  [2][64][156]
  float2* W = (float2*)(ws + 102480000);          // 1,280,000 B twiddle table
  const float* w = (const float*)d_in[0];
  const float* o = (const float*)d_in[1];

  setup_kernel<<<dim3(625), dim3(256), 0, stream>>>(W);
  f1_kernel<<<dim3(BATCH * 64), dim3(256), 0, stream>>>(w, o, G, W);
  f2_kernel<<<dim3(BATCH * 157), dim3(256), 0, stream>>>(G, X, W);
  i1_kernel<<<dim3(BATCH * NB * 157), dim3(256), 0, stream>>>(X, H, W);
  hipMemsetAsync(E, 0, 2 * BATCH * NB * NHOPS * sizeof(float), stream);
  i2_kernel<<<dim3(BATCH * NB * 64), dim3(256), 0, stream>>>(H, E, W);
  finalize_kernel<<<dim3(1), dim3(256), 0, stream>>>(E, (float*)d_out);
}